// Round 1
// 223.114 us; speedup vs baseline: 1.0271x; 1.0271x over previous
//
#include <hip/hip_runtime.h>

// Fused MS-SSIM + L1, single pass. B=128, H=W=384 fp32.
// Levels k=1,2,4,7, box conv, zero pad p=k/2 (even k -> 385x385 output).
// Round 8: VALU diet (counters: VALUBusy 77%, HBM 14% -> VALU-issue-bound).
//  (a) P/M basis: track {Sp,Sm,Spp,Smm} of P=X+Y, M=X-Y (4 quantities, not 5).
//      SxSy=(Sp^2-Sm^2)/4, Sx^2+Sy^2=(Sp^2+Sm^2)/2, Sxy=(Spp-Smm)/4,
//      Sxx+Syy=(Spp+Smm)/2, |Sx-Sy|=|Sm|. Exact (linear in the summed terms).
//  (b) Pair-shift horizontal trees: t=v+sh1(v); sh2(t)=e2+e3; sh4(t)=e4+e5;
//      sh6(v)=e6. 4 bpermutes + 4 adds per quantity (was 6+6), and squares
//      are formed BEFORE shifting (shift commutes with elementwise square),
//      killing the 21 per-shift product muls (now 2 per row).
//  (c) Running vertical sums: V = w + Vsum; Vsum = V - ring[last]. 2 ops vs
//      6 (k7) / 3 (k4). Rings keep depth 3/6 so the 6-phase unroll still
//      renames rotations for free. fp-reassociation drift ~1e-5 rel, averaged
//      over 18.9M samples.
// Load pipeline (r7-validated): 6-slot RAW register ring, load(u+3) ->
// stage(u+1) -> compute(u); vmcnt anchor at first true use. Ownership masks,
// grid (7,2,128), block partials + final double reduce unchanged.

#define W 384
#define H 384
#define NB 128
#define BAND 48
#define NTILES 7
#define NBLK (NTILES * 2 * NB)   // grid (7,2,128) = 1792 blocks

__device__ __forceinline__ float bp(int addr, float v) {
    return __int_as_float(__builtin_amdgcn_ds_bpermute(addr, __float_as_int(v)));
}

// SSIM for window k*k from UNNORMALIZED P/M sums V={Sp,Sm,Spp,Smm}.
// Doubled-constant form: c1k42 = 2*C1*k^4, c2k42 = 2*C2*k^4. Using
// (2A1*2A2)/(2B1*2B2) = S, with 2A1 = (Sp^2-Sm^2) + 2C1k^4, etc.
__device__ __forceinline__ float ssim_pm(const float* V, float k2, float c1k42, float c2k42) {
    const float p2 = V[0] * V[0];
    const float m2 = V[1] * V[1];
    const float d  = p2 - m2;              // 4*Sx*Sy
    const float s  = p2 + m2;              // 2*(Sx^2+Sy^2)
    const float dq = V[2] - V[3];          // 4*Sxy
    const float sq = V[2] + V[3];          // 2*(Sxx+Syy)
    const float A1 = d + c1k42;
    const float B1 = s + c1k42;
    const float A2 = fmaf(k2, dq, -d) + c2k42;
    const float B2 = fmaf(k2, sq, -s) + c2k42;
    return (A1 * A2) * __builtin_amdgcn_rcpf(B1 * B2);
}

__global__ __launch_bounds__(256) void msssim_main(
    const float* __restrict__ X, const float* __restrict__ Y,
    const float* __restrict__ dr, float* __restrict__ part)
{
    const int lane = threadIdx.x & 63;
    const int wv   = threadIdx.x >> 6;          // 0..3
    const int tile = blockIdx.x;                // 0..6
    const int band = blockIdx.y * 4 + wv;       // 0..7
    const int b    = blockIdx.z;

    const int cbase = -3 + 56 * tile;           // window-start col of lane 0
    const int c     = cbase + lane;             // this lane's column
    const int R0    = BAND * band;

    // per-level output-row bounds (wave-uniform):
    const int g1hi  = R0 + 48;                       // k1,k7: [R0, R0+48)
    const int g24hi = (band == 7) ? 385 : R0 + 48;   // k2,k4: [R0, g24hi)

    const float drb = dr[b];
    const float C1 = (0.01f * drb) * (0.01f * drb);
    const float C2 = (0.03f * drb) * (0.03f * drb);
    const float tC1 = 2.f * C1;                        // k=1 (2*C1)
    const float C1_2 = C1 * 32.f,    C2_2 = C2 * 32.f;    // k=2: 2*k^4
    const float C1_4 = C1 * 512.f,   C2_4 = C2 * 512.f;   // k=4
    const float C1_7 = C1 * 4802.f,  C2_7 = C2 * 4802.f;  // k=7

    // ownership masks (validated rounds 2-7): output col j = c + k/2
    const float m1 = (lane >= 3 && lane <= 58 && c     <= 383) ? 1.f : 0.f;
    const float m2 = (lane >= 2 && lane <= 57 && c + 1 <= 384) ? 1.f : 0.f;
    const float m4 = (lane >= 1 && lane <= 56 && c + 2 <= 384) ? 1.f : 0.f;
    const float m7 = (             lane <= 55 && c + 3 <= 383) ? 1.f : 0.f;

    // own-column load setup (clamped offset + zero mask, row-invariant)
    const float mcol = (c >= 0 && c < W) ? 1.f : 0.f;
    const int   cc   = c < 0 ? 0 : (c > W - 1 ? W - 1 : c);

    // bpermute byte addresses for shifts 1,2,4,6 (hw wraps mod 64; wrapped
    // lanes produce garbage excluded by the ownership masks)
    const int a1 = ((lane + 1) & 63) << 2;
    const int a2 = ((lane + 2) & 63) << 2;
    const int a4 = ((lane + 4) & 63) << 2;
    const int a6 = ((lane + 6) & 63) << 2;

    const float* __restrict__ Xb = X + (size_t)b * (H * W);
    const float* __restrict__ Yb = Y + (size_t)b * (H * W);

    // vertical state per quantity q in {p,m,pp,mm}:
    //   r2: w2 of previous row
    //   r4 ring (depth 3) + running sum v4s = sum w4 of rows u-3..u-1
    //   r7 ring (depth 6) + running sum v7s = sum w7 of rows u-6..u-1
    float r2[4], r4[3][4], r7[6][4], v4s[4], v7s[4];
#pragma unroll
    for (int q = 0; q < 4; ++q) {
        r2[q] = 0.f;
        r4[0][q] = r4[1][q] = r4[2][q] = 0.f;
#pragma unroll
        for (int a = 0; a < 6; ++a) r7[a][q] = 0.f;
        v4s[q] = 0.f; v7s[q] = 0.f;
    }

    float ss1 = 0.f, ss2 = 0.f, ss4 = 0.f, ss7 = 0.f, l1 = 0.f;

    const int u0 = R0 - 3;        // 54 steps: u in [R0-3, R0+50]

    // 6-slot raw-value ring: slot s holds row r with (r - u0) % 6 == s.
    float px[6], py[6];
    auto loadv = [&](int u, float& x, float& y) {
        if (u >= 0 && u < H) {               // wave-uniform branch
            x = Xb[(size_t)u * W + cc];
            y = Yb[(size_t)u * W + cc];
        } else { x = 0.f; y = 0.f; }
    };

    // A/B staged sets, filled at step t-1, consumed at step t.
    // layout: [0..3]=w2[q], [4..7]=w4[q], [8..11]=w7[q], [12]=pp0, [13]=mm0
    float SA[14], SB[14];
    auto stage = [&](float xr, float yr, float* S) {
        const float pv  = (xr + yr) * mcol;
        const float mv  = (xr - yr) * mcol;
        const float ppv = pv * pv;
        const float mmv = mv * mv;
        S[12] = ppv; S[13] = mmv;
        const float qv[4] = { pv, mv, ppv, mmv };
#pragma unroll
        for (int q = 0; q < 4; ++q) {
            const float v   = qv[q];
            const float sh1 = bp(a1, v);        // e1
            const float t   = v + sh1;          // e0+e1
            const float sh2 = bp(a2, t);        // e2+e3
            const float sh4 = bp(a4, t);        // e4+e5
            const float sh6 = bp(a6, v);        // e6
            const float w4  = t + sh2;
            S[q]     = t;                       // w2
            S[4 + q] = w4;
            S[8 + q] = w4 + (sh4 + sh6);        // w7
        }
    };

    // prologue: preload rows u0..u0+2; stage row u0 into A
    loadv(u0,     px[0], py[0]);
    loadv(u0 + 1, px[1], py[1]);
    loadv(u0 + 2, px[2], py[2]);
    stage(px[0], py[0], SA);

    for (int s = 0; s < 54; s += 6) {
#pragma unroll
        for (int ph = 0; ph < 6; ++ph) {
            const int u = u0 + s + ph;       // compute row

            // stage 1: load row u+3 into slot (ph+3)%6  (gap 2 to stage)
            loadv(u + 3, px[(ph + 3) % 6], py[(ph + 3) % 6]);

            // stage 2: shift row u+1 (slot (ph+1)%6, loaded 2 steps ago)
            const bool evenT = ((ph & 1) == 0);
            float* Sn       = evenT ? SB : SA;
            const float* Sv = evenT ? SA : SB;
            stage(px[(ph + 1) % 6], py[(ph + 1) % 6], Sn);

            // stage 3: vertical windows for row u from the set staged last step
            float V2[4], V4[4], V7[4];
#pragma unroll
            for (int q = 0; q < 4; ++q) {
                const float w2v = Sv[q], w4v = Sv[4 + q], w7v = Sv[8 + q];
                V2[q] = w2v + r2[q];  r2[q] = w2v;
                const float a4v = w4v + v4s[q];
                V4[q] = a4v;  v4s[q] = a4v - r4[2][q];
                r4[2][q] = r4[1][q]; r4[1][q] = r4[0][q]; r4[0][q] = w4v;
                const float a7v = w7v + v7s[q];
                V7[q] = a7v;  v7s[q] = a7v - r7[5][q];
                r7[5][q] = r7[4][q]; r7[4][q] = r7[3][q]; r7[3][q] = r7[2][q];
                r7[2][q] = r7[1][q]; r7[1][q] = r7[0][q]; r7[0][q] = w7v;
            }

            // k=1 (closed form from pp0, mm0): pp0-mm0=4xy, pp0+mm0=2(x^2+y^2)
            if (u >= R0 && u < g1hi) {
                const float num = (Sv[12] - Sv[13]) + tC1;
                const float den = (Sv[12] + Sv[13]) + tC1;
                ss1 = fmaf(num * __builtin_amdgcn_rcpf(den), m1, ss1);
            }
            // k=2, i=u
            if (u >= R0 && u < g24hi) {
                ss2 = fmaf(ssim_pm(V2, 4.f, C1_2, C2_2), m2, ss2);
            }
            // k=4, i=u-1
            {
                const int i = u - 1;
                if (i >= R0 && i < g24hi) {
                    ss4 = fmaf(ssim_pm(V4, 16.f, C1_4, C2_4), m4, ss4);
                }
            }
            // k=7, i=u-3, plus L1 (|Sx-Sy| = |Sm| = |V7m|, 1/49 in reduce)
            {
                const int i = u - 3;
                if (i >= R0 && i < g1hi) {
                    ss7 = fmaf(ssim_pm(V7, 49.f, C1_7, C2_7), m7, ss7);
                    l1  = fmaf(fabsf(V7[1]), m7, l1);
                }
            }
        }
    }

    // wave reduce -> block reduce -> one float store per block per quantity
#pragma unroll
    for (int d = 32; d > 0; d >>= 1) {
        ss1 += __shfl_down(ss1, d, 64);
        ss2 += __shfl_down(ss2, d, 64);
        ss4 += __shfl_down(ss4, d, 64);
        ss7 += __shfl_down(ss7, d, 64);
        l1  += __shfl_down(l1,  d, 64);
    }
    __shared__ float sred[4][5];
    if (lane == 0) {
        sred[wv][0] = ss1; sred[wv][1] = ss2; sred[wv][2] = ss4;
        sred[wv][3] = ss7; sred[wv][4] = l1;
    }
    __syncthreads();
    if (threadIdx.x == 0) {
        const int bid = ((int)blockIdx.z * 2 + (int)blockIdx.y) * NTILES + (int)blockIdx.x;
#pragma unroll
        for (int q = 0; q < 5; ++q)
            part[bid * 5 + q] = sred[0][q] + sred[1][q] + sred[2][q] + sred[3][q];
    }
}

__global__ __launch_bounds__(256) void reduce_final(
    const float* __restrict__ part, float* __restrict__ out)
{
    const int lane = threadIdx.x & 63;
    const int wv   = threadIdx.x >> 6;
    double d[5] = {0, 0, 0, 0, 0};
    for (int i = threadIdx.x; i < NBLK; i += 256) {
#pragma unroll
        for (int q = 0; q < 5; ++q) d[q] += (double)part[i * 5 + q];
    }
#pragma unroll
    for (int s = 32; s > 0; s >>= 1) {
#pragma unroll
        for (int q = 0; q < 5; ++q) d[q] += __shfl_down(d[q], s, 64);
    }
    __shared__ double sd[4][5];
    if (lane == 0) {
#pragma unroll
        for (int q = 0; q < 5; ++q) sd[wv][q] = d[q];
    }
    __syncthreads();
    if (threadIdx.x == 0) {
        double a[5];
#pragma unroll
        for (int q = 0; q < 5; ++q)
            a[q] = sd[0][q] + sd[1][q] + sd[2][q] + sd[3][q];
        const double n384 = (double)NB * 384.0 * 384.0;
        const double n385 = (double)NB * 385.0 * 385.0;
        const double m  = (a[0] / n384) * (a[1] / n385) * (a[2] / n385) * (a[3] / n384);
        const double l1 = a[4] / 49.0 / n384;
        out[0] = (float)(0.84 * (1.0 - m) + 0.16 * l1);
    }
}

extern "C" void kernel_launch(void* const* d_in, const int* in_sizes, int n_in,
                              void* d_out, int out_size, void* d_ws, size_t ws_size,
                              hipStream_t stream) {
    const float* X  = (const float*)d_in[0];
    const float* Y  = (const float*)d_in[1];
    const float* dr = (const float*)d_in[2];
    float* out  = (float*)d_out;
    float* part = (float*)d_ws;   // NBLK*5 floats = 35.8 KB

    dim3 grid(NTILES, 2, NB);
    msssim_main<<<grid, 256, 0, stream>>>(X, Y, dr, part);
    reduce_final<<<1, 256, 0, stream>>>(part, out);
}

// Round 2
// 209.581 us; speedup vs baseline: 1.0934x; 1.0646x over previous
//
#include <hip/hip_runtime.h>

// Fused MS-SSIM + L1, single pass. B=128, H=W=384 fp32.
// Levels k=1,2,4,7, box conv, zero pad p=k/2 (even k -> 385x385 output).
// Round 9: DS-latency fix. r8 cut VALU 77->47% but dur was flat: the
// pair-shift tree added dependent bpermute chains (sh1->t->sh2(t)) with only
// 1 step of slack, and raised DS ops 12->16/step. At ~2.25 waves/SIMD the
// chained lgkm latency dominates. This round:
//  (a) FLAT shifts d=1..6 of p,m only (12 independent bpermutes); squares
//      taken POST-shift (shift commutes with square) -> same values, same
//      add groupings as r8 (absmax stays 0), DS 16->12, dependency depth 1.
//  (b) 2-step bpermute pipeline: 3 stage buffers (mod-3 rotation, compile
//      time under the 6-phase unroll). Step u: load(u+4) -> consume(u)
//      [single lgkmcnt(12) wait, results issued ~1.5 steps ago] ->
//      stage(u+2) [raw bperm issue, no arithmetic on results].
//      Stage AFTER consume keeps the needed wait <= 12 (4-bit lgkmcnt).
//  (c) Keep r8's validated P/M basis, running vertical sums, ownership
//      masks, grid (7,2,128), block partials + double final reduce.

#define W 384
#define H 384
#define NB 128
#define BAND 48
#define NTILES 7
#define NBLK (NTILES * 2 * NB)   // grid (7,2,128) = 1792 blocks

__device__ __forceinline__ float bp(int addr, float v) {
    return __int_as_float(__builtin_amdgcn_ds_bpermute(addr, __float_as_int(v)));
}

// SSIM for window k*k from UNNORMALIZED P/M sums V={Sp,Sm,Spp,Smm}.
// Doubled-constant form: c1k42 = 2*C1*k^4, c2k42 = 2*C2*k^4.
__device__ __forceinline__ float ssim_pm(const float* V, float k2, float c1k42, float c2k42) {
    const float p2 = V[0] * V[0];
    const float m2 = V[1] * V[1];
    const float d  = p2 - m2;              // 4*Sx*Sy
    const float s  = p2 + m2;              // 2*(Sx^2+Sy^2)
    const float dq = V[2] - V[3];          // 4*Sxy
    const float sq = V[2] + V[3];          // 2*(Sxx+Syy)
    const float A1 = d + c1k42;
    const float B1 = s + c1k42;
    const float A2 = fmaf(k2, dq, -d) + c2k42;
    const float B2 = fmaf(k2, sq, -s) + c2k42;
    return (A1 * A2) * __builtin_amdgcn_rcpf(B1 * B2);
}

__global__ __launch_bounds__(256) void msssim_main(
    const float* __restrict__ X, const float* __restrict__ Y,
    const float* __restrict__ dr, float* __restrict__ part)
{
    const int lane = threadIdx.x & 63;
    const int wv   = threadIdx.x >> 6;          // 0..3
    const int tile = blockIdx.x;                // 0..6
    const int band = blockIdx.y * 4 + wv;       // 0..7
    const int b    = blockIdx.z;

    const int cbase = -3 + 56 * tile;           // window-start col of lane 0
    const int c     = cbase + lane;             // this lane's column
    const int R0    = BAND * band;

    // per-level output-row bounds (wave-uniform):
    const int g1hi  = R0 + 48;                       // k1,k7: [R0, R0+48)
    const int g24hi = (band == 7) ? 385 : R0 + 48;   // k2,k4: [R0, g24hi)

    const float drb = dr[b];
    const float C1 = (0.01f * drb) * (0.01f * drb);
    const float C2 = (0.03f * drb) * (0.03f * drb);
    const float tC1 = 2.f * C1;                        // k=1 (2*C1)
    const float C1_2 = C1 * 32.f,    C2_2 = C2 * 32.f;    // k=2: 2*k^4
    const float C1_4 = C1 * 512.f,   C2_4 = C2 * 512.f;   // k=4
    const float C1_7 = C1 * 4802.f,  C2_7 = C2 * 4802.f;  // k=7

    // ownership masks (validated rounds 2-8): output col j = c + k/2
    const float m1 = (lane >= 3 && lane <= 58 && c     <= 383) ? 1.f : 0.f;
    const float m2 = (lane >= 2 && lane <= 57 && c + 1 <= 384) ? 1.f : 0.f;
    const float m4 = (lane >= 1 && lane <= 56 && c + 2 <= 384) ? 1.f : 0.f;
    const float m7 = (             lane <= 55 && c + 3 <= 383) ? 1.f : 0.f;

    // own-column load setup (clamped offset + zero mask, row-invariant)
    const float mcol = (c >= 0 && c < W) ? 1.f : 0.f;
    const int   cc   = c < 0 ? 0 : (c > W - 1 ? W - 1 : c);

    // bpermute byte addresses for shifts d=1..6 (hw wraps mod 64; wrapped
    // lanes produce garbage excluded by the ownership masks)
    int ad[6];
#pragma unroll
    for (int d = 1; d <= 6; ++d) ad[d - 1] = ((lane + d) & 63) << 2;

    const float* __restrict__ Xb = X + (size_t)b * (H * W);
    const float* __restrict__ Yb = Y + (size_t)b * (H * W);

    // vertical state per quantity q in {p,m,pp,mm}:
    //   r2: w2 of previous row
    //   r4 ring (depth 3) + running sum v4s = sum w4 of rows u-3..u-1
    //   r7 ring (depth 6) + running sum v7s = sum w7 of rows u-6..u-1
    float r2[4], r4[3][4], r7[6][4], v4s[4], v7s[4];
#pragma unroll
    for (int q = 0; q < 4; ++q) {
        r2[q] = 0.f;
        r4[0][q] = r4[1][q] = r4[2][q] = 0.f;
#pragma unroll
        for (int a = 0; a < 6; ++a) r7[a][q] = 0.f;
        v4s[q] = 0.f; v7s[q] = 0.f;
    }

    float ss1 = 0.f, ss2 = 0.f, ss4 = 0.f, ss7 = 0.f, l1 = 0.f;

    const int u0 = R0 - 3;        // 54 steps: u in [R0-3, R0+50]

    // 6-slot raw-value ring: slot holds row r with (r - u0) % 6 == slot.
    float px[6], py[6];
    auto loadv = [&](int u, float& x, float& y) {
        if (u >= 0 && u < H) {               // wave-uniform branch
            x = Xb[(size_t)u * W + cc];
            y = Yb[(size_t)u * W + cc];
        } else { x = 0.f; y = 0.f; }
    };

    // 3 stage buffers, row r -> SBuf[(r-u0)%3].
    // layout: [0]=pv, [1..6]=sh1..sh6(pv), [7]=mv, [8..13]=sh1..sh6(mv).
    // bperm results land RAW (no arithmetic at stage) so the lgkm wait
    // sinks to the consume 2 steps later.
    float SBuf[3][14];
    auto stageRow = [&](float xr, float yr, float* S) {
        const float pv = (xr + yr) * mcol;
        const float mv = (xr - yr) * mcol;
        S[0] = pv; S[7] = mv;
#pragma unroll
        for (int d = 1; d <= 6; ++d) {
            S[d]     = bp(ad[d - 1], pv);
            S[7 + d] = bp(ad[d - 1], mv);
        }
    };

    // prologue: rows u0..u0+3 loaded; rows u0, u0+1 staged
    loadv(u0,     px[0], py[0]);
    loadv(u0 + 1, px[1], py[1]);
    loadv(u0 + 2, px[2], py[2]);
    loadv(u0 + 3, px[3], py[3]);
    stageRow(px[0], py[0], SBuf[0]);
    stageRow(px[1], py[1], SBuf[1]);

    for (int s = 0; s < 54; s += 6) {
#pragma unroll
        for (int ph = 0; ph < 6; ++ph) {
            const int u = u0 + s + ph;       // compute row

            // 1. issue loads for row u+4 (2-step gap to their use at stage)
            loadv(u + 4, px[(ph + 4) % 6], py[(ph + 4) % 6]);

            // 2. consume row u (staged 2 steps ago)
            const float* S = SBuf[ph % 3];
            float ep2[7], em2[7];
#pragma unroll
            for (int i = 0; i < 7; ++i) {
                ep2[i] = S[i] * S[i];             // == shifted(pv^2), exact
                em2[i] = S[7 + i] * S[7 + i];
            }
            float w2q[4], w4q[4], w7q[4];
            auto tree = [&](const float* e, int q) {
                const float w2v = e[0] + e[1];
                const float w4v = w2v + (e[2] + e[3]);
                const float w7v = w4v + ((e[4] + e[5]) + e[6]);
                w2q[q] = w2v; w4q[q] = w4v; w7q[q] = w7v;
            };
            tree(S, 0);          // p
            tree(S + 7, 1);      // m
            tree(ep2, 2);        // pp
            tree(em2, 3);        // mm

            float V2[4], V4[4], V7[4];
#pragma unroll
            for (int q = 0; q < 4; ++q) {
                const float w2v = w2q[q], w4v = w4q[q], w7v = w7q[q];
                V2[q] = w2v + r2[q];  r2[q] = w2v;
                const float a4v = w4v + v4s[q];
                V4[q] = a4v;  v4s[q] = a4v - r4[2][q];
                r4[2][q] = r4[1][q]; r4[1][q] = r4[0][q]; r4[0][q] = w4v;
                const float a7v = w7v + v7s[q];
                V7[q] = a7v;  v7s[q] = a7v - r7[5][q];
                r7[5][q] = r7[4][q]; r7[4][q] = r7[3][q]; r7[3][q] = r7[2][q];
                r7[2][q] = r7[1][q]; r7[1][q] = r7[0][q]; r7[0][q] = w7v;
            }

            // k=1 (closed form): pp0-mm0=4xy, pp0+mm0=2(x^2+y^2)
            if (u >= R0 && u < g1hi) {
                const float num = (ep2[0] - em2[0]) + tC1;
                const float den = (ep2[0] + em2[0]) + tC1;
                ss1 = fmaf(num * __builtin_amdgcn_rcpf(den), m1, ss1);
            }
            // k=2, i=u
            if (u >= R0 && u < g24hi) {
                ss2 = fmaf(ssim_pm(V2, 4.f, C1_2, C2_2), m2, ss2);
            }
            // k=4, i=u-1
            {
                const int i = u - 1;
                if (i >= R0 && i < g24hi) {
                    ss4 = fmaf(ssim_pm(V4, 16.f, C1_4, C2_4), m4, ss4);
                }
            }
            // k=7, i=u-3, plus L1 (|Sx-Sy| = |Sm|, 1/49 in reduce)
            {
                const int i = u - 3;
                if (i >= R0 && i < g1hi) {
                    ss7 = fmaf(ssim_pm(V7, 49.f, C1_7, C2_7), m7, ss7);
                    l1  = fmaf(fabsf(V7[1]), m7, l1);
                }
            }

            // 3. stage row u+2 (raw bperm issue; consumed 2 steps later)
            stageRow(px[(ph + 2) % 6], py[(ph + 2) % 6], SBuf[(ph + 2) % 3]);
        }
    }

    // wave reduce -> block reduce -> one float store per block per quantity
#pragma unroll
    for (int d = 32; d > 0; d >>= 1) {
        ss1 += __shfl_down(ss1, d, 64);
        ss2 += __shfl_down(ss2, d, 64);
        ss4 += __shfl_down(ss4, d, 64);
        ss7 += __shfl_down(ss7, d, 64);
        l1  += __shfl_down(l1,  d, 64);
    }
    __shared__ float sred[4][5];
    if (lane == 0) {
        sred[wv][0] = ss1; sred[wv][1] = ss2; sred[wv][2] = ss4;
        sred[wv][3] = ss7; sred[wv][4] = l1;
    }
    __syncthreads();
    if (threadIdx.x == 0) {
        const int bid = ((int)blockIdx.z * 2 + (int)blockIdx.y) * NTILES + (int)blockIdx.x;
#pragma unroll
        for (int q = 0; q < 5; ++q)
            part[bid * 5 + q] = sred[0][q] + sred[1][q] + sred[2][q] + sred[3][q];
    }
}

__global__ __launch_bounds__(256) void reduce_final(
    const float* __restrict__ part, float* __restrict__ out)
{
    const int lane = threadIdx.x & 63;
    const int wv   = threadIdx.x >> 6;
    double d[5] = {0, 0, 0, 0, 0};
    for (int i = threadIdx.x; i < NBLK; i += 256) {
#pragma unroll
        for (int q = 0; q < 5; ++q) d[q] += (double)part[i * 5 + q];
    }
#pragma unroll
    for (int s = 32; s > 0; s >>= 1) {
#pragma unroll
        for (int q = 0; q < 5; ++q) d[q] += __shfl_down(d[q], s, 64);
    }
    __shared__ double sd[4][5];
    if (lane == 0) {
#pragma unroll
        for (int q = 0; q < 5; ++q) sd[wv][q] = d[q];
    }
    __syncthreads();
    if (threadIdx.x == 0) {
        double a[5];
#pragma unroll
        for (int q = 0; q < 5; ++q)
            a[q] = sd[0][q] + sd[1][q] + sd[2][q] + sd[3][q];
        const double n384 = (double)NB * 384.0 * 384.0;
        const double n385 = (double)NB * 385.0 * 385.0;
        const double m  = (a[0] / n384) * (a[1] / n385) * (a[2] / n385) * (a[3] / n384);
        const double l1 = a[4] / 49.0 / n384;
        out[0] = (float)(0.84 * (1.0 - m) + 0.16 * l1);
    }
}

extern "C" void kernel_launch(void* const* d_in, const int* in_sizes, int n_in,
                              void* d_out, int out_size, void* d_ws, size_t ws_size,
                              hipStream_t stream) {
    const float* X  = (const float*)d_in[0];
    const float* Y  = (const float*)d_in[1];
    const float* dr = (const float*)d_in[2];
    float* out  = (float*)d_out;
    float* part = (float*)d_ws;   // NBLK*5 floats = 35.8 KB

    dim3 grid(NTILES, 2, NB);
    msssim_main<<<grid, 256, 0, stream>>>(X, Y, dr, part);
    reduce_final<<<1, 256, 0, stream>>>(part, out);
}

// Round 3
// 201.145 us; speedup vs baseline: 1.1393x; 1.0419x over previous
//
#include <hip/hip_runtime.h>

// Fused MS-SSIM + L1, single pass. B=128, H=W=384 fp32.
// Levels k=1,2,4,7, box conv, zero pad p=k/2 (even k -> 385x385 output).
// Round 10: 2 columns/lane + packed-f32. r9 is VALU-issue-bound (~217
// instrs/step for ONE output col; VALUBusy 68%, HBM 18%, DS conflicts 0).
// This round amortizes all per-step overhead over 2 adjacent columns and
// uses gfx950 packed fp32 (v_pk_*_f32 via float2 ext_vector):
//  - wave covers a 112-col strip; lane owns window-starts i0=112s-4+2l (even)
//    and i1=i0+1. Loads are one aligned dwordx2 per image per row.
//  - shifts need lanes l+1..l+3 only: 12 bpermutes per step for TWO cols
//    (6/col vs 12/col). Squares still post-shift (exactness + B2>0 safety).
//  - vertical rings, running sums, and all 4 SSIM evals operate on
//    column-packed float2 -> ~half the emitted instructions.
//  - pipeline = r9's validated schedule: load(u+4) -> consume(u) ->
//    stage(u+2); 3-slot load ring, 3 stage buffers, mod-3/mod-2 indices
//    compile-time under the 6-phase unroll.
// Ownership: strip s owns outputs j in [112s, min(112s+112, Jmax_k));
// j = i + k/2 per col. Owned lanes have l <= 57 -> shift sources <= 60, no
// wrap. Grid (4,2,128) = 1024 blocks.

#define W 384
#define H 384
#define NB 128
#define BAND 48
#define NSTRIPS 4
#define NBLK (NSTRIPS * 2 * NB)

typedef __attribute__((ext_vector_type(2))) float f2;

__device__ __forceinline__ float bp(int addr, float v) {
    return __int_as_float(__builtin_amdgcn_ds_bpermute(addr, __float_as_int(v)));
}

__device__ __forceinline__ f2 f2s(float v) { f2 r; r.x = v; r.y = v; return r; }

// Column-packed SSIM from UNNORMALIZED P/M sums (per quantity, f2 = 2 cols).
// Doubled-constant form: c1k42 = 2*C1*k^4, c2k42 = 2*C2*k^4.
__device__ __forceinline__ f2 ssim_pm2(f2 Vp, f2 Vm, f2 Vpp, f2 Vmm,
                                       float k2, float c1k42, float c2k42) {
    const f2 p2 = Vp * Vp;
    const f2 m2 = Vm * Vm;
    const f2 d  = p2 - m2;              // 4*Sx*Sy
    const f2 s  = p2 + m2;              // 2*(Sx^2+Sy^2)
    const f2 dq = Vpp - Vmm;            // 4*Sxy
    const f2 sq = Vpp + Vmm;            // 2*(Sxx+Syy)
    const f2 A1 = d + c1k42;
    const f2 B1 = s + c1k42;
    const f2 A2 = __builtin_elementwise_fma(f2s(k2), dq, -d) + c2k42;
    const f2 B2 = __builtin_elementwise_fma(f2s(k2), sq, -s) + c2k42;
    const f2 num = A1 * A2;
    const f2 den = B1 * B2;
    f2 r;
    r.x = num.x * __builtin_amdgcn_rcpf(den.x);
    r.y = num.y * __builtin_amdgcn_rcpf(den.y);
    return r;
}

__global__ __launch_bounds__(256) void msssim_main(
    const float* __restrict__ X, const float* __restrict__ Y,
    const float* __restrict__ dr, float* __restrict__ part)
{
    const int lane = threadIdx.x & 63;
    const int wv   = threadIdx.x >> 6;          // 0..3
    const int strip= blockIdx.x;                // 0..3
    const int band = blockIdx.y * 4 + wv;       // 0..7
    const int b    = blockIdx.z;

    const int i0 = 112 * strip - 4 + 2 * lane;  // even window-start col
    const int i1 = i0 + 1;
    const int R0 = BAND * band;

    // per-level output-row bounds (wave-uniform), validated r2-r9:
    const int g1hi  = R0 + 48;                       // k1,k7 rows
    const int g24hi = (band == 7) ? 385 : R0 + 48;   // k2,k4 rows

    const float drb = dr[b];
    const float C1 = (0.01f * drb) * (0.01f * drb);
    const float C2 = (0.03f * drb) * (0.03f * drb);
    const float tC1 = 2.f * C1;                           // k=1
    const float C1_2 = C1 * 32.f,    C2_2 = C2 * 32.f;    // 2*k^4, k=2
    const float C1_4 = C1 * 512.f,   C2_4 = C2 * 512.f;   // k=4
    const float C1_7 = C1 * 4802.f,  C2_7 = C2 * 4802.f;  // k=7

    // ownership masks: strip owns output j in [112s, min(112s+112, Jmax_k))
    const int lo   = 112 * strip;
    const int hi17 = (lo + 112 < 384) ? lo + 112 : 384;   // k1,k7 Jmax=384
    const int hi24 = (lo + 112 < 385) ? lo + 112 : 385;   // k2,k4 Jmax=385
    auto own = [&](int j, int hi) -> float {
        return (j >= lo && j < hi) ? 1.f : 0.f;
    };
    const f2 mk1 = { own(i0,     hi17), own(i1,     hi17) };
    const f2 mk2 = { own(i0 + 1, hi24), own(i1 + 1, hi24) };
    const f2 mk4 = { own(i0 + 2, hi24), own(i1 + 2, hi24) };
    const f2 mk7 = { own(i0 + 3, hi17), own(i1 + 3, hi17) };

    // load mask/clamp (row-invariant); cE even -> 8B-aligned f2 loads
    f2 mc;
    mc.x = (i0 >= 0 && i0 < W) ? 1.f : 0.f;
    mc.y = (i1 >= 0 && i1 < W) ? 1.f : 0.f;
    const int cE = i0 < 0 ? 0 : (i0 > W - 2 ? W - 2 : i0);

    // bpermute byte addresses, lane distances 1..3 (wrap excluded by masks)
    const int ba1 = ((lane + 1) & 63) << 2;
    const int ba2 = ((lane + 2) & 63) << 2;
    const int ba3 = ((lane + 3) & 63) << 2;

    const float* __restrict__ Xr = X + (size_t)b * (H * W) + cE;
    const float* __restrict__ Yr = Y + (size_t)b * (H * W) + cE;

    // vertical state per quantity q in {p,m,pp,mm}, column-packed f2:
    f2 r2[4], r4[3][4], r7[6][4], v4s[4], v7s[4];
#pragma unroll
    for (int q = 0; q < 4; ++q) {
        r2[q] = f2s(0.f);
        r4[0][q] = r4[1][q] = r4[2][q] = f2s(0.f);
#pragma unroll
        for (int a = 0; a < 6; ++a) r7[a][q] = f2s(0.f);
        v4s[q] = f2s(0.f); v7s[q] = f2s(0.f);
    }

    f2 ss1v = f2s(0.f), ss2v = f2s(0.f), ss4v = f2s(0.f),
       ss7v = f2s(0.f), l1v  = f2s(0.f);

    const int u0 = R0 - 3;        // 54 steps: u in [R0-3, R0+50]

    // 3-slot load ring (row r -> slot (r-u0)%3), f2 per image
    f2 rx[3], ry[3];
    auto loadv = [&](int u, int slot) {
        if (u >= 0 && u < H) {               // wave-uniform branch
            rx[slot] = *(const f2*)(Xr + (size_t)u * W);
            ry[slot] = *(const f2*)(Yr + (size_t)u * W);
        } else { rx[slot] = f2s(0.f); ry[slot] = f2s(0.f); }
    };

    // 3 stage buffers (row r -> buf (r-u0)%3): own p,m (f2) + 12 raw bperms
    // sr layout: [0..5]=pa1,pb1,pa2,pb2,pa3,pb3  [6..11]=ma1..mb3
    f2 sp[3], sm[3];
    float sr[3][12];
    auto stageRow = [&](int ps, int bs) {
        const f2 p = (rx[ps] + ry[ps]) * mc;
        const f2 m = (rx[ps] - ry[ps]) * mc;
        sp[bs] = p; sm[bs] = m;
        sr[bs][0]  = bp(ba1, p.x);  sr[bs][1]  = bp(ba1, p.y);
        sr[bs][2]  = bp(ba2, p.x);  sr[bs][3]  = bp(ba2, p.y);
        sr[bs][4]  = bp(ba3, p.x);  sr[bs][5]  = bp(ba3, p.y);
        sr[bs][6]  = bp(ba1, m.x);  sr[bs][7]  = bp(ba1, m.y);
        sr[bs][8]  = bp(ba2, m.x);  sr[bs][9]  = bp(ba2, m.y);
        sr[bs][10] = bp(ba3, m.x);  sr[bs][11] = bp(ba3, m.y);
    };

    // horizontal windows for 2 cols from 8 cols [v0.x,v0.y,e2..e7]
    auto hwin = [&](f2 v0, float e2, float e3, float e4, float e5,
                    float e6, float e7, f2& w2, f2& w4, f2& w7) {
        const float w2a = v0.x + v0.y;
        const float w2b = v0.y + e2;
        const float t1  = e2 + e3;
        const float w4a = w2a + t1;
        const float t1b = e3 + e4;
        const float w4b = w2b + t1b;
        const float t2  = e4 + e5;
        const float w7a = (w4a + t2) + e6;
        const float t3  = e5 + e6;
        const float w7b = (w4b + t3) + e7;
        w2.x = w2a; w2.y = w2b;
        w4.x = w4a; w4.y = w4b;
        w7.x = w7a; w7.y = w7b;
    };

    // prologue: load u0..u0+2 (slots 0,1,2); stage u0,u0+1; reload slot 0
    loadv(u0,     0);
    loadv(u0 + 1, 1);
    loadv(u0 + 2, 2);
    stageRow(0, 0);
    stageRow(1, 1);
    loadv(u0 + 3, 0);     // slot (3)%3 = 0; row u0 already staged

    for (int s = 0; s < 54; s += 6) {
#pragma unroll
        for (int ph = 0; ph < 6; ++ph) {
            const int u = u0 + s + ph;       // compute row
            // s % 6 == 0, so (s+ph) mod 3 == ph mod 3: compile-time slots.

            // 1. issue loads for row u+4 -> slot (ph+4)%3 == (ph+1)%3
            loadv(u + 4, (ph + 1) % 3);

            // 2. consume row u from buf ph%3 (staged 2 steps ago)
            const int cb = ph % 3;
            const f2 p0 = sp[cb], m0 = sm[cb];
            const float pa1 = sr[cb][0],  pb1 = sr[cb][1];
            const float pa2 = sr[cb][2],  pb2 = sr[cb][3];
            const float pa3 = sr[cb][4],  pb3 = sr[cb][5];
            const float ma1 = sr[cb][6],  mb1 = sr[cb][7];
            const float ma2 = sr[cb][8],  mb2 = sr[cb][9];
            const float ma3 = sr[cb][10], mb3 = sr[cb][11];

            const f2 pp0 = p0 * p0;
            const f2 mm0 = m0 * m0;

            f2 W2[4], W4[4], W7[4];
            hwin(p0,  pa1, pb1, pa2, pb2, pa3, pb3, W2[0], W4[0], W7[0]);
            hwin(m0,  ma1, mb1, ma2, mb2, ma3, mb3, W2[1], W4[1], W7[1]);
            hwin(pp0, pa1*pa1, pb1*pb1, pa2*pa2, pb2*pb2, pa3*pa3, pb3*pb3,
                 W2[2], W4[2], W7[2]);
            hwin(mm0, ma1*ma1, mb1*mb1, ma2*ma2, mb2*mb2, ma3*ma3, mb3*mb3,
                 W2[3], W4[3], W7[3]);

            f2 V2[4], V4[4], V7[4];
#pragma unroll
            for (int q = 0; q < 4; ++q) {
                V2[q] = W2[q] + r2[q];  r2[q] = W2[q];
                const f2 a4v = W4[q] + v4s[q];
                V4[q] = a4v;  v4s[q] = a4v - r4[2][q];
                r4[2][q] = r4[1][q]; r4[1][q] = r4[0][q]; r4[0][q] = W4[q];
                const f2 a7v = W7[q] + v7s[q];
                V7[q] = a7v;  v7s[q] = a7v - r7[5][q];
                r7[5][q] = r7[4][q]; r7[4][q] = r7[3][q]; r7[3][q] = r7[2][q];
                r7[2][q] = r7[1][q]; r7[1][q] = r7[0][q]; r7[0][q] = W7[q];
            }

            // k=1 (closed form): pp0-mm0=4xy, pp0+mm0=2(x^2+y^2)
            if (u >= R0 && u < g1hi) {
                const f2 num = (pp0 - mm0) + tC1;
                const f2 den = (pp0 + mm0) + tC1;
                f2 s1;
                s1.x = num.x * __builtin_amdgcn_rcpf(den.x);
                s1.y = num.y * __builtin_amdgcn_rcpf(den.y);
                ss1v = __builtin_elementwise_fma(s1, mk1, ss1v);
            }
            // k=2, i=u
            if (u >= R0 && u < g24hi) {
                ss2v = __builtin_elementwise_fma(
                    ssim_pm2(V2[0], V2[1], V2[2], V2[3], 4.f, C1_2, C2_2),
                    mk2, ss2v);
            }
            // k=4, i=u-1
            {
                const int i = u - 1;
                if (i >= R0 && i < g24hi) {
                    ss4v = __builtin_elementwise_fma(
                        ssim_pm2(V4[0], V4[1], V4[2], V4[3], 16.f, C1_4, C2_4),
                        mk4, ss4v);
                }
            }
            // k=7, i=u-3, plus L1 (|Sx-Sy| = |Sm|, 1/49 in reduce)
            {
                const int i = u - 3;
                if (i >= R0 && i < g1hi) {
                    ss7v = __builtin_elementwise_fma(
                        ssim_pm2(V7[0], V7[1], V7[2], V7[3], 49.f, C1_7, C2_7),
                        mk7, ss7v);
                    f2 av; av.x = fabsf(V7[1].x); av.y = fabsf(V7[1].y);
                    l1v = __builtin_elementwise_fma(av, mk7, l1v);
                }
            }

            // 3. stage row u+2: slot (ph+2)%3 -> buf (ph+2)%3
            stageRow((ph + 2) % 3, (ph + 2) % 3);
        }
    }

    // combine column pair, then wave reduce -> block reduce -> store
    float ss1 = ss1v.x + ss1v.y;
    float ss2 = ss2v.x + ss2v.y;
    float ss4 = ss4v.x + ss4v.y;
    float ss7 = ss7v.x + ss7v.y;
    float l1  = l1v.x  + l1v.y;
#pragma unroll
    for (int d = 32; d > 0; d >>= 1) {
        ss1 += __shfl_down(ss1, d, 64);
        ss2 += __shfl_down(ss2, d, 64);
        ss4 += __shfl_down(ss4, d, 64);
        ss7 += __shfl_down(ss7, d, 64);
        l1  += __shfl_down(l1,  d, 64);
    }
    __shared__ float sred[4][5];
    if (lane == 0) {
        sred[wv][0] = ss1; sred[wv][1] = ss2; sred[wv][2] = ss4;
        sred[wv][3] = ss7; sred[wv][4] = l1;
    }
    __syncthreads();
    if (threadIdx.x == 0) {
        const int bid = ((int)blockIdx.z * 2 + (int)blockIdx.y) * NSTRIPS + (int)blockIdx.x;
#pragma unroll
        for (int q = 0; q < 5; ++q)
            part[bid * 5 + q] = sred[0][q] + sred[1][q] + sred[2][q] + sred[3][q];
    }
}

__global__ __launch_bounds__(256) void reduce_final(
    const float* __restrict__ part, float* __restrict__ out)
{
    const int lane = threadIdx.x & 63;
    const int wv   = threadIdx.x >> 6;
    double d[5] = {0, 0, 0, 0, 0};
    for (int i = threadIdx.x; i < NBLK; i += 256) {
#pragma unroll
        for (int q = 0; q < 5; ++q) d[q] += (double)part[i * 5 + q];
    }
#pragma unroll
    for (int s = 32; s > 0; s >>= 1) {
#pragma unroll
        for (int q = 0; q < 5; ++q) d[q] += __shfl_down(d[q], s, 64);
    }
    __shared__ double sd[4][5];
    if (lane == 0) {
#pragma unroll
        for (int q = 0; q < 5; ++q) sd[wv][q] = d[q];
    }
    __syncthreads();
    if (threadIdx.x == 0) {
        double a[5];
#pragma unroll
        for (int q = 0; q < 5; ++q)
            a[q] = sd[0][q] + sd[1][q] + sd[2][q] + sd[3][q];
        const double n384 = (double)NB * 384.0 * 384.0;
        const double n385 = (double)NB * 385.0 * 385.0;
        const double m  = (a[0] / n384) * (a[1] / n385) * (a[2] / n385) * (a[3] / n384);
        const double l1 = a[4] / 49.0 / n384;
        out[0] = (float)(0.84 * (1.0 - m) + 0.16 * l1);
    }
}

extern "C" void kernel_launch(void* const* d_in, const int* in_sizes, int n_in,
                              void* d_out, int out_size, void* d_ws, size_t ws_size,
                              hipStream_t stream) {
    const float* X  = (const float*)d_in[0];
    const float* Y  = (const float*)d_in[1];
    const float* dr = (const float*)d_in[2];
    float* out  = (float*)d_out;
    float* part = (float*)d_ws;   // NBLK*5 floats = 20.5 KB

    dim3 grid(NSTRIPS, 2, NB);
    msssim_main<<<grid, 256, 0, stream>>>(X, Y, dr, part);
    reduce_final<<<1, 256, 0, stream>>>(part, out);
}